// Round 1
// baseline (346.037 us; speedup 1.0000x reference)
//
#include <hip/hip_runtime.h>

// B=4, S=2048, D=1024, scale = 1/sqrt(64) = 0.125
// Workspace layout (105 MB): identical to previous round.
//   [0,16M)    Xbf  : features bf16              [8192,1024]
//   [16M,24M)  Wcat bf16: Wq|Wk|Wv|Wo            4 x [1024,1024]
//   [24M,40M)  Q bf16 [8192,1024]  -> reused as attn
//   [40M,56M)  K bf16
//   [56M,72M)  Vt bf16 (V transposed)            [4][1024,2048]
//   [72M,104M) P~ bf16 dense [4][2048,2048]
//   [104M,+32K) lsum fp32 [8192]
//
// R7: 256x{256,128} 8-phase GEMM (T3+T4+T5 from the CDNA4 guide's m201
// template), replacing the 128^2 2-barrier structure (~570 TF measured).
// Schedule per K-tile t (4 quadrant phases, h=M-half, g=N-half):
//   q0 reads A0,B0 | stages A1(t+1)     q1 reads A0,B1 | stages B1(t+1)
//   q2 reads A1,B0 | stages A0(t+2)     q3 reads A1,B1 | stages B0(t+2)
// Interleaved wave mapping (wave wm covers rows of BOTH halves at
// h*128+wm*64; wn covers cols g*NH+wn*NW) makes each quadrant touch exactly
// one A-half and one B-half, so every stage targets a region whose last read
// was a strictly earlier phase (write-after-read safe across the mid-phase
// barrier + lgkmcnt(0)). vmcnt(2+NL) once per K-tile (q3, before the end
// barrier) retires tile t+1's loads while leaving tile t+2's 2 half-tiles in
// flight — never vmcnt(0) in the main loop. Raw s_barrier (not
// __syncthreads) so the compiler can't re-insert a vmcnt(0) drain.
// Rotation swizzle (phys quad p=(q+r)&7) kept from R6: measured 0 bank
// conflicts.

using u16 = unsigned short;
typedef __bf16 bf16x8 __attribute__((ext_vector_type(8)));
typedef float f32x4 __attribute__((ext_vector_type(4)));

#define AS1 __attribute__((address_space(1)))
#define AS3 __attribute__((address_space(3)))

__device__ inline u16 f2bf(float f) {
  union { float f; unsigned int u; } c; c.f = f;
  unsigned int u = c.u;
  u += 0x7fffu + ((u >> 16) & 1u);   // round-to-nearest-even
  return (u16)(u >> 16);
}

// one launch: casts features + all 4 weight matrices, and zeroes lsum
__global__ __launch_bounds__(256) void cast_all(
    const float4* __restrict__ feat, const float4* __restrict__ wq,
    const float4* __restrict__ wk, const float4* __restrict__ wv,
    const float4* __restrict__ wo, ushort4* __restrict__ xbf,
    ushort4* __restrict__ wcat, float* __restrict__ lsum) {
  const int b = blockIdx.x, tx = threadIdx.x;
  if (b >= 12288) {                      // 32 trailing blocks zero lsum[8192]
    lsum[(b - 12288) * 256 + tx] = 0.f;
    return;
  }
  const float4* src; ushort4* dst; int idx;
  if (b < 8192) { src = feat; dst = xbf; idx = b * 256 + tx; }
  else {
    const int w = (b - 8192) >> 10, loc = ((b - 8192) & 1023) * 256 + tx;
    src = (w == 0) ? wq : (w == 1) ? wk : (w == 2) ? wv : wo;
    dst = wcat + w * 262144; idx = loc;
  }
  float4 v = src[idx];
  ushort4 o;
  o.x = f2bf(v.x); o.y = f2bf(v.y); o.z = f2bf(v.z); o.w = f2bf(v.w);
  dst[idx] = o;
}

// MODE 2: fp32 row-major + bias (out-proj)
// MODE 3: fused QKV epilogue (Q->C, K->C2, Vt->C3 transposed-batched)
// MODE 4: bf16 row-major, acc * 1/lsum[row] (PV normalize)
// MODE 5: exp(scale*acc) bf16 + atomic row sums (scores)
template <int MODE, int BN>
__global__ __launch_bounds__(512, 2) void gemm8p(
    const u16* __restrict__ A, const u16* __restrict__ Bm, void* __restrict__ C,
    void* __restrict__ C2, void* __restrict__ C3,
    const float* __restrict__ bias, const float* __restrict__ bias2,
    const float* __restrict__ bias3, float* __restrict__ lsum,
    int M, int N, int K, int lda, int ldc, float scale,
    long long sA, long long sB, long long sC)
{
  constexpr int NL  = BN / 128;   // B gloads per wave per half-tile
  constexpr int NFH = BN / 128;   // N fragments per half per wave
  constexpr int NH  = BN / 2;     // N half width
  constexpr int NW  = NH / 4;     // per-wave N sub-stride

  __shared__ u16 As[2 * 256 * 64];
  __shared__ u16 Bs[2 * BN * 64];

  const int tx = threadIdx.x;
  const int wave = tx >> 6, lane = tx & 63;
  const int wm = wave >> 2, wn = wave & 3;
  const int fr = lane & 15, fq = lane >> 4;
  const int lr = lane >> 3, lp = lane & 7;
  const int m0 = blockIdx.y * 256, n0 = blockIdx.x * BN;
  const u16* Ab = A + blockIdx.z * sA + (long long)m0 * lda;
  const u16* Bb = Bm + blockIdx.z * sB + (long long)n0 * K;
  const int NT = K >> 6;   // number of 64-wide K-tiles (all shapes: >= 16)

  f32x4 acc[8][2 * NFH] = {};

  // stage half-tile h of K-tile t.  LDS dest is wave-uniform (HW adds
  // lane*16B); per-lane global source is pre-rotated: physical quad lp of
  // tile-row R holds logical quad (lp-R)&7.
  auto stageA = [&](int t, int h) {
#pragma unroll
    for (int s = 0; s < 2; ++s) {
      const int R = h * 128 + wave * 16 + s * 8 + lr;
      const int q = (lp - R) & 7;
      __builtin_amdgcn_global_load_lds(
          (const AS1 void*)(Ab + (long long)R * lda + t * 64 + q * 8),
          (AS3 void*)(As + (t & 1) * 16384 + (h * 128 + wave * 16 + s * 8) * 64),
          16, 0, 0);
    }
  };
  auto stageB = [&](int t, int h) {
#pragma unroll
    for (int s = 0; s < NL; ++s) {
      const int R = h * NH + wave * (8 * NL) + s * 8 + lr;
      const int q = (lp - R) & 7;
      __builtin_amdgcn_global_load_lds(
          (const AS1 void*)(Bb + (long long)R * K + t * 64 + q * 8),
          (AS3 void*)(Bs + (t & 1) * (BN * 64) + (h * NH + wave * (8 * NL) + s * 8) * 64),
          16, 0, 0);
    }
  };

  // prologue: tile 0 complete + first halves of tile 1; wait tile 0 landed
  // (allow A0(1)+B0(1) = 2+NL loads outstanding), fence all waves.
  stageA(0, 0); stageA(0, 1); stageB(0, 0); stageB(0, 1);
  stageA(1, 0); stageB(1, 0);
  if constexpr (BN == 256) asm volatile("s_waitcnt vmcnt(4)" ::: "memory");
  else                     asm volatile("s_waitcnt vmcnt(3)" ::: "memory");
  __builtin_amdgcn_s_barrier();

  for (int t = 0; t < NT; ++t) {
    const u16* At = As + (t & 1) * 16384;
    const u16* Bt = Bs + (t & 1) * (BN * 64);
#pragma unroll
    for (int qp = 0; qp < 4; ++qp) {
      const int h = qp >> 1, g = qp & 1;
      bf16x8 af[4][2], bv[NFH][2];
#pragma unroll
      for (int fi = 0; fi < 4; ++fi) {
        const int R = h * 128 + wm * 64 + fi * 16 + fr;
#pragma unroll
        for (int s = 0; s < 2; ++s)
          af[fi][s] = *(const bf16x8*)(At + R * 64 + (((s * 4 + fq + R) & 7) << 3));
      }
#pragma unroll
      for (int fj = 0; fj < NFH; ++fj) {
        const int R = g * NH + wn * NW + fj * 16 + fr;
#pragma unroll
        for (int s = 0; s < 2; ++s)
          bv[fj][s] = *(const bf16x8*)(Bt + R * 64 + (((s * 4 + fq + R) & 7) << 3));
      }
      // half-tile prefetch for this phase (see schedule comment above)
      if (qp == 0)      { if (t + 1 < NT) stageA(t + 1, 1); }
      else if (qp == 1) { if (t + 1 < NT) stageB(t + 1, 1); }
      else if (qp == 2) { if (t + 2 < NT) stageA(t + 2, 0); }
      else              { if (t + 2 < NT) stageB(t + 2, 0); }

      __builtin_amdgcn_s_barrier();
      asm volatile("s_waitcnt lgkmcnt(0)" ::: "memory");
      __builtin_amdgcn_sched_barrier(0);
      __builtin_amdgcn_s_setprio(1);
#pragma unroll
      for (int s = 0; s < 2; ++s)
#pragma unroll
        for (int fi = 0; fi < 4; ++fi)
#pragma unroll
          for (int fj = 0; fj < NFH; ++fj)
            acc[h * 4 + fi][g * NFH + fj] = __builtin_amdgcn_mfma_f32_16x16x32_bf16(
                af[fi][s], bv[fj][s], acc[h * 4 + fi][g * NFH + fj], 0, 0, 0);
      __builtin_amdgcn_s_setprio(0);
      if (qp == 3) {
        // once per K-tile: retire tile t+1's loads; leave tile t+2's two
        // half-tiles (2+NL loads) in flight across the barrier.
        if constexpr (BN == 256) asm volatile("s_waitcnt vmcnt(4)" ::: "memory");
        else                     asm volatile("s_waitcnt vmcnt(3)" ::: "memory");
      }
      __builtin_amdgcn_s_barrier();
    }
  }

  // epilogue: C/D layout col=lane&15, row=(lane>>4)*4+reg
  const int col = lane & 15, rq = (lane >> 4) << 2;
  const long long zC = (long long)blockIdx.z * sC;

  if constexpr (MODE == 5) {
#pragma unroll
    for (int i = 0; i < 8; ++i) {
      const int gmb = m0 + (i >> 2) * 128 + wm * 64 + (i & 3) * 16 + rq;
      float rs[4] = {0.f, 0.f, 0.f, 0.f};
#pragma unroll
      for (int j = 0; j < 2 * NFH; ++j) {
        const int gn = n0 + (j / NFH) * NH + wn * NW + (j % NFH) * 16 + col;
#pragma unroll
        for (int r = 0; r < 4; ++r) {
          const float e = __expf(acc[i][j][r] * scale);
          ((u16*)C)[zC + (long long)(gmb + r) * ldc + gn] = f2bf(e);
          rs[r] += e;
        }
      }
#pragma unroll
      for (int r = 0; r < 4; ++r) {
        float s = rs[r];
        s += __shfl_xor(s, 1); s += __shfl_xor(s, 2);
        s += __shfl_xor(s, 4); s += __shfl_xor(s, 8);
        if (col == 0)
          atomicAdd(&lsum[(long long)blockIdx.z * 2048 + gmb + r], s);
      }
    }
  } else if constexpr (MODE == 4) {
#pragma unroll
    for (int i = 0; i < 8; ++i) {
      const int gmb = m0 + (i >> 2) * 128 + wm * 64 + (i & 3) * 16 + rq;
      float inv[4];
#pragma unroll
      for (int r = 0; r < 4; ++r)
        inv[r] = 1.0f / lsum[(long long)blockIdx.z * 2048 + gmb + r];
#pragma unroll
      for (int j = 0; j < 2 * NFH; ++j) {
        const int gn = n0 + (j / NFH) * NH + wn * NW + (j % NFH) * 16 + col;
#pragma unroll
        for (int r = 0; r < 4; ++r)
          ((u16*)C)[zC + (long long)(gmb + r) * ldc + gn] = f2bf(acc[i][j][r] * inv[r]);
      }
    }
  } else if constexpr (MODE == 3) {
    const int sect = n0 >> 10;  // 0=Q 1=K 2=V (n0 256-aligned, uniform)
#pragma unroll
    for (int i = 0; i < 8; ++i) {
      const int gmb = m0 + (i >> 2) * 128 + wm * 64 + (i & 3) * 16 + rq;
#pragma unroll
      for (int j = 0; j < 2 * NFH; ++j) {
        const int gn = n0 + (j / NFH) * NH + wn * NW + (j % NFH) * 16 + col;
        const int nb = gn & 1023;
        const float bvv = (sect == 0) ? bias[nb] : (sect == 1) ? bias2[nb] : bias3[nb];
#pragma unroll
        for (int r = 0; r < 4; ++r) {
          const int gm = gmb + r;
          const float v = acc[i][j][r] + bvv;
          if (sect == 0) {
            ((u16*)C)[(long long)gm * 1024 + nb] = f2bf(v);
          } else if (sect == 1) {
            ((u16*)C2)[(long long)gm * 1024 + nb] = f2bf(v);
          } else {
            const int bb = gm >> 11, tt = gm & 2047;
            ((u16*)C3)[((long long)bb << 21) + (long long)nb * 2048 + tt] = f2bf(v);
          }
        }
      }
    }
  } else {  // MODE == 2: fp32 row-major + bias
#pragma unroll
    for (int i = 0; i < 8; ++i) {
      const int gmb = m0 + (i >> 2) * 128 + wm * 64 + (i & 3) * 16 + rq;
#pragma unroll
      for (int j = 0; j < 2 * NFH; ++j) {
        const int gn = n0 + (j / NFH) * NH + wn * NW + (j % NFH) * 16 + col;
        const float bvv = bias[gn];
#pragma unroll
        for (int r = 0; r < 4; ++r)
          ((float*)C)[zC + (long long)(gmb + r) * ldc + gn] = acc[i][j][r] + bvv;
      }
    }
  }
}

extern "C" void kernel_launch(void* const* d_in, const int* in_sizes, int n_in,
                              void* d_out, int out_size, void* d_ws, size_t ws_size,
                              hipStream_t stream) {
  (void)in_sizes; (void)n_in; (void)out_size; (void)ws_size;
  const float* feat = (const float*)d_in[0];
  const float* Wq = (const float*)d_in[1];
  const float* bq = (const float*)d_in[2];
  const float* Wk = (const float*)d_in[3];
  const float* bk = (const float*)d_in[4];
  const float* Wv = (const float*)d_in[5];
  const float* bv = (const float*)d_in[6];
  const float* Wo = (const float*)d_in[7];
  const float* bo = (const float*)d_in[8];
  float* out = (float*)d_out;

  char* ws = (char*)d_ws;
  const unsigned long long MB = 1024ull * 1024ull;
  u16* Xbf  = (u16*)(ws);
  u16* Wcat = (u16*)(ws + 16 * MB);           // Wq|Wk|Wv|Wo bf16
  u16* Wob  = Wcat + 3ll * 1024 * 1024;
  u16* Q    = (u16*)(ws + 24 * MB);           // reused as attn later
  u16* Kbuf = (u16*)(ws + 40 * MB);
  u16* Vt   = (u16*)(ws + 56 * MB);
  u16* P    = (u16*)(ws + 72 * MB);           // dense bf16 [4][2048,2048]
  float* lsum = (float*)(ws + 104 * MB);      // [8192]
  u16* attn = Q;

  // casts (features + 4 weights) + lsum zeroing in one launch
  cast_all<<<12320, 256, 0, stream>>>((const float4*)feat, (const float4*)Wq,
                                      (const float4*)Wk, (const float4*)Wv,
                                      (const float4*)Wo, (ushort4*)Xbf,
                                      (ushort4*)Wcat, lsum);

  // fused QKV projection: N=3072 over Wq|Wk|Wv; V written transposed
  gemm8p<3, 256><<<dim3(12, 32, 1), 512, 0, stream>>>(
      Xbf, Wcat, Q, Kbuf, Vt, bq, bk, bv, nullptr,
      8192, 3072, 1024, 1024, 0, 1.f, 0, 0, 0);

  // P~ = exp(Q K^T * 0.125) bf16 + row sums -> lsum (all 4 batches)
  gemm8p<5, 256><<<dim3(8, 8, 4), 512, 0, stream>>>(
      Q, Kbuf, P, nullptr, nullptr, nullptr, nullptr, nullptr, lsum,
      2048, 2048, 1024, 1024, 2048, 0.125f,
      2048ll * 1024, 2048ll * 1024, 2048ll * 2048);

  // attn = (P~ @ V) / lsum  (batched; B operand is Vt)
  gemm8p<4, 128><<<dim3(8, 8, 4), 512, 0, stream>>>(
      P, Vt, attn, nullptr, nullptr, nullptr, nullptr, nullptr, lsum,
      2048, 1024, 2048, 2048, 1024, 1.f,
      2048ll * 2048, 1024ll * 2048, 2048ll * 1024);

  // out = attn @ Wo^T + bo  (fp32 output)
  gemm8p<2, 128><<<dim3(8, 32, 1), 512, 0, stream>>>(
      attn, Wob, out, nullptr, nullptr, bo, nullptr, nullptr, nullptr,
      8192, 1024, 1024, 1024, 1024, 1.f, 0, 0, 0);
}

// Round 2
// 333.914 us; speedup vs baseline: 1.0363x; 1.0363x over previous
//
#include <hip/hip_runtime.h>

// B=4, S=2048, D=1024, scale = 1/sqrt(64) = 0.125
// Workspace layout (105 MB): identical to previous rounds.
//   [0,16M)    Xbf  : features bf16              [8192,1024]
//   [16M,24M)  Wcat bf16: Wq|Wk|Wv|Wo            4 x [1024,1024]
//   [24M,40M)  Q bf16 [8192,1024]  -> reused as attn
//   [40M,56M)  K bf16
//   [56M,72M)  Vt bf16 (V transposed)            [4][1024,2048]
//   [72M,104M) P~ bf16 dense [4][2048,2048]
//   [104M,+32K) lsum fp32 [8192]
//
// R8: reg-cached 8-phase 256xBN GEMM. R1's defect: 48 ds_read_b128 per
// K-tile per wave (every quadrant re-read its A/B halves) -> LDS pipe
// (4608 cyc/CU/K-tile) >> MFMA (2484) -> lockstep alternation -> 13% Mfma.
// Fix: quadrant order (0,0),(0,1),(1,1),(1,0) with fragments held in regs:
//   p0: read afA(h0) + bv0(g0)        | stage A1(t+1) | MFMA h0g0
//   p1: read bv1(g1) + afB chunk1     | stage B1(t+1) | MFMA h0g1
//   p2: read afB chunk2 + re-read bv0 | stage A0(t+2) | MFMA h1g1
//   p3: (no reads)                    | stage B0(t+2) | MFMA h1g0, vmcnt(N)
// 28 reads/K-tile (MF=8) or 20 (MF=4). Wave tiles interleaved across LDS
// halves (wave wmi owns rows {h*128 + wmi*(WTM/2)+[0,WTM/2): h=0,1}) so each
// phase reads exactly one A-half/one B-half; same-buffer stages (t+2 A0@p2,
// B0@p3) land >=1 barrier after that region's last read (p0) -> WAR-safe.
// vmcnt(NLA+NLB) once per K-tile, never 0 in the loop. Rotation swizzle
// (phys quad p=(q+R)&7) kept: measured 0 bank conflicts.

using u16 = unsigned short;
typedef __bf16 bf16x8 __attribute__((ext_vector_type(8)));
typedef float f32x4 __attribute__((ext_vector_type(4)));

#define AS1 __attribute__((address_space(1)))
#define AS3 __attribute__((address_space(3)))

__device__ inline u16 f2bf(float f) {
  union { float f; unsigned int u; } c; c.f = f;
  unsigned int u = c.u;
  u += 0x7fffu + ((u >> 16) & 1u);   // round-to-nearest-even
  return (u16)(u >> 16);
}

// one launch: casts features + all 4 weight matrices, and zeroes lsum
__global__ __launch_bounds__(256) void cast_all(
    const float4* __restrict__ feat, const float4* __restrict__ wq,
    const float4* __restrict__ wk, const float4* __restrict__ wv,
    const float4* __restrict__ wo, ushort4* __restrict__ xbf,
    ushort4* __restrict__ wcat, float* __restrict__ lsum) {
  const int b = blockIdx.x, tx = threadIdx.x;
  if (b >= 12288) {                      // 32 trailing blocks zero lsum[8192]
    lsum[(b - 12288) * 256 + tx] = 0.f;
    return;
  }
  const float4* src; ushort4* dst; int idx;
  if (b < 8192) { src = feat; dst = xbf; idx = b * 256 + tx; }
  else {
    const int w = (b - 8192) >> 10, loc = ((b - 8192) & 1023) * 256 + tx;
    src = (w == 0) ? wq : (w == 1) ? wk : (w == 2) ? wv : wo;
    dst = wcat + w * 262144; idx = loc;
  }
  float4 v = src[idx];
  ushort4 o;
  o.x = f2bf(v.x); o.y = f2bf(v.y); o.z = f2bf(v.z); o.w = f2bf(v.w);
  dst[idx] = o;
}

// MODE 2: fp32 row-major + bias (out-proj)
// MODE 3: fused QKV epilogue (Q->C, K->C2, Vt->C3 transposed-batched)
// MODE 4: bf16 row-major, acc * 1/lsum[row] (PV normalize)
// MODE 5: exp(scale*acc) bf16 + atomic row sums (scores)
template <int MODE, int BN>
__global__ __launch_bounds__(512, 2) void gemm8p(
    const u16* __restrict__ A, const u16* __restrict__ Bm, void* __restrict__ C,
    void* __restrict__ C2, void* __restrict__ C3,
    const float* __restrict__ bias, const float* __restrict__ bias2,
    const float* __restrict__ bias3, float* __restrict__ lsum,
    int M, int N, int K, int lda, int ldc, float scale,
    long long sA, long long sB, long long sC)
{
  constexpr int WM  = (BN == 256) ? 2 : 4;
  constexpr int WN  = 8 / WM;
  constexpr int WTM = 256 / WM;        // 128 or 64
  constexpr int MF  = WTM / 16;        // 8 or 4 (acc M-frags)
  constexpr int MFH = MF / 2;          // frags per A-half: 4 or 2
  constexpr int MFQ = MFH / 2;         // afB chunk1 size: 2 or 1
  constexpr int NLA = 2;               // A gloads/lane per half-tile
  constexpr int NLB = BN / 128;        // B gloads/lane per half-tile
  constexpr int VMC = NLA + NLB;       // loads left in flight at K-tile end

  __shared__ u16 As[2 * 256 * 64];
  __shared__ u16 Bs[2 * BN * 64];

  const int tx = threadIdx.x;
  const int wave = tx >> 6, lane = tx & 63;
  const int wmi = wave & (WM - 1), wni = wave / WM;
  const int fr = lane & 15, fq = lane >> 4;
  const int lr = lane >> 3, lp = lane & 7;
  const int m0 = blockIdx.y * 256, n0 = blockIdx.x * BN;
  const u16* Ab = A + blockIdx.z * sA + (long long)m0 * lda;
  const u16* Bb = Bm + blockIdx.z * sB + (long long)n0 * K;
  const int NT = K >> 6;   // 64-wide K-tiles (>= 16 for all shapes)

  f32x4 acc[MF][4] = {};
  bf16x8 afA[MFH][2], afB[MFH][2], bv0[2][2], bv1[2][2];

  // stage half-tile h of K-tile t. LDS dest wave-uniform (HW adds lane*16B);
  // per-lane global source pre-rotated: phys quad lp of row R holds logical
  // quad (lp-R)&7.
  auto stageA = [&](int t, int h) {
#pragma unroll
    for (int s2 = 0; s2 < NLA; ++s2) {
      const int R = h * 128 + wave * (8 * NLA) + s2 * 8 + lr;
      const int q = (lp - R) & 7;
      __builtin_amdgcn_global_load_lds(
          (const AS1 void*)(Ab + (long long)R * lda + t * 64 + q * 8),
          (AS3 void*)(As + (t & 1) * 16384 +
                      (h * 128 + wave * (8 * NLA) + s2 * 8) * 64),
          16, 0, 0);
    }
  };
  auto stageB = [&](int t, int h) {
#pragma unroll
    for (int s2 = 0; s2 < NLB; ++s2) {
      const int R = h * (BN / 2) + wave * (8 * NLB) + s2 * 8 + lr;
      const int q = (lp - R) & 7;
      __builtin_amdgcn_global_load_lds(
          (const AS1 void*)(Bb + (long long)R * K + t * 64 + q * 8),
          (AS3 void*)(Bs + (t & 1) * (BN * 64) +
                      (h * (BN / 2) + wave * (8 * NLB) + s2 * 8) * 64),
          16, 0, 0);
    }
  };
  auto ldf = [&](const u16* base, int R, int s) {
    return *(const bf16x8*)(base + R * 64 + (((s * 4 + fq + R) & 7) << 3));
  };

  // prologue: tile 0 complete + first halves of tile 1; retire tile 0
  // (leave NLA+NLB of tile 1 outstanding), fence all waves.
  stageA(0, 0); stageA(0, 1); stageB(0, 0); stageB(0, 1);
  stageA(1, 0); stageB(1, 0);
  if constexpr (VMC == 4) asm volatile("s_waitcnt vmcnt(4)" ::: "memory");
  else                    asm volatile("s_waitcnt vmcnt(3)" ::: "memory");
  __builtin_amdgcn_s_barrier();

  for (int t = 0; t < NT; ++t) {
    const u16* At = As + (t & 1) * 16384;
    const u16* Bt = Bs + (t & 1) * (BN * 64);

    // ---- phase 0: (h0,g0) — read afA + bv0; stage A1(t+1)
#pragma unroll
    for (int u = 0; u < MFH; ++u) {
      const int R = wmi * (WTM / 2) + u * 16 + fr;
      afA[u][0] = ldf(At, R, 0); afA[u][1] = ldf(At, R, 1);
    }
#pragma unroll
    for (int v = 0; v < 2; ++v) {
      const int R = wni * 32 + v * 16 + fr;
      bv0[v][0] = ldf(Bt, R, 0); bv0[v][1] = ldf(Bt, R, 1);
    }
    if (t + 1 < NT) stageA(t + 1, 1);
    __builtin_amdgcn_s_barrier();
    asm volatile("s_waitcnt lgkmcnt(0)" ::: "memory");
    __builtin_amdgcn_sched_barrier(0);
    __builtin_amdgcn_s_setprio(1);
#pragma unroll
    for (int s = 0; s < 2; ++s)
#pragma unroll
      for (int u = 0; u < MFH; ++u)
#pragma unroll
        for (int v = 0; v < 2; ++v)
          acc[u][v] = __builtin_amdgcn_mfma_f32_16x16x32_bf16(
              afA[u][s], bv0[v][s], acc[u][v], 0, 0, 0);
    __builtin_amdgcn_s_setprio(0);
    __builtin_amdgcn_s_barrier();

    // ---- phase 1: (h0,g1) — read bv1 + afB chunk1; stage B1(t+1)
#pragma unroll
    for (int v = 0; v < 2; ++v) {
      const int R = (BN / 2) + wni * 32 + v * 16 + fr;
      bv1[v][0] = ldf(Bt, R, 0); bv1[v][1] = ldf(Bt, R, 1);
    }
#pragma unroll
    for (int u = 0; u < MFQ; ++u) {
      const int R = 128 + wmi * (WTM / 2) + u * 16 + fr;
      afB[u][0] = ldf(At, R, 0); afB[u][1] = ldf(At, R, 1);
    }
    if (t + 1 < NT) stageB(t + 1, 1);
    __builtin_amdgcn_s_barrier();
    asm volatile("s_waitcnt lgkmcnt(0)" ::: "memory");
    __builtin_amdgcn_sched_barrier(0);
    __builtin_amdgcn_s_setprio(1);
#pragma unroll
    for (int s = 0; s < 2; ++s)
#pragma unroll
      for (int u = 0; u < MFH; ++u)
#pragma unroll
        for (int v = 0; v < 2; ++v)
          acc[u][2 + v] = __builtin_amdgcn_mfma_f32_16x16x32_bf16(
              afA[u][s], bv1[v][s], acc[u][2 + v], 0, 0, 0);
    __builtin_amdgcn_s_setprio(0);
    __builtin_amdgcn_s_barrier();

    // ---- phase 2: (h1,g1) — read afB chunk2 + re-read bv0; stage A0(t+2)
#pragma unroll
    for (int u = MFQ; u < MFH; ++u) {
      const int R = 128 + wmi * (WTM / 2) + u * 16 + fr;
      afB[u][0] = ldf(At, R, 0); afB[u][1] = ldf(At, R, 1);
    }
#pragma unroll
    for (int v = 0; v < 2; ++v) {
      const int R = wni * 32 + v * 16 + fr;
      bv0[v][0] = ldf(Bt, R, 0); bv0[v][1] = ldf(Bt, R, 1);
    }
    if (t + 2 < NT) stageA(t + 2, 0);
    __builtin_amdgcn_s_barrier();
    asm volatile("s_waitcnt lgkmcnt(0)" ::: "memory");
    __builtin_amdgcn_sched_barrier(0);
    __builtin_amdgcn_s_setprio(1);
#pragma unroll
    for (int s = 0; s < 2; ++s)
#pragma unroll
      for (int u = 0; u < MFH; ++u)
#pragma unroll
        for (int v = 0; v < 2; ++v)
          acc[MFH + u][2 + v] = __builtin_amdgcn_mfma_f32_16x16x32_bf16(
              afB[u][s], bv1[v][s], acc[MFH + u][2 + v], 0, 0, 0);
    __builtin_amdgcn_s_setprio(0);
    __builtin_amdgcn_s_barrier();

    // ---- phase 3: (h1,g0) — no reads; stage B0(t+2); K-tile vmcnt
    if (t + 2 < NT) stageB(t + 2, 0);
    __builtin_amdgcn_s_barrier();
    asm volatile("s_waitcnt lgkmcnt(0)" ::: "memory");
    __builtin_amdgcn_sched_barrier(0);
    __builtin_amdgcn_s_setprio(1);
#pragma unroll
    for (int s = 0; s < 2; ++s)
#pragma unroll
      for (int u = 0; u < MFH; ++u)
#pragma unroll
        for (int v = 0; v < 2; ++v)
          acc[MFH + u][v] = __builtin_amdgcn_mfma_f32_16x16x32_bf16(
              afB[u][s], bv0[v][s], acc[MFH + u][v], 0, 0, 0);
    __builtin_amdgcn_s_setprio(0);
    // retire tile t+1's loads; leave tile t+2's 2 half-tiles in flight.
    if constexpr (VMC == 4) asm volatile("s_waitcnt vmcnt(4)" ::: "memory");
    else                    asm volatile("s_waitcnt vmcnt(3)" ::: "memory");
    __builtin_amdgcn_s_barrier();
  }

  // epilogue: C/D layout col=lane&15, row=(lane>>4)*4+reg
  // acc[i][j]: gm = m0 + (i/MFH)*128 + wmi*(WTM/2) + (i%MFH)*16 + rq + r
  //            gn = n0 + (j>>1)*(BN/2) + wni*32 + (j&1)*16 + col
  const int col = lane & 15, rq = (lane >> 4) << 2;
  const long long zC = (long long)blockIdx.z * sC;

  if constexpr (MODE == 5) {
#pragma unroll
    for (int i = 0; i < MF; ++i) {
      const int gmb = m0 + (i / MFH) * 128 + wmi * (WTM / 2) + (i % MFH) * 16 + rq;
      float rs[4] = {0.f, 0.f, 0.f, 0.f};
#pragma unroll
      for (int j = 0; j < 4; ++j) {
        const int gn = n0 + (j >> 1) * (BN / 2) + wni * 32 + (j & 1) * 16 + col;
#pragma unroll
        for (int r = 0; r < 4; ++r) {
          const float e = __expf(acc[i][j][r] * scale);
          ((u16*)C)[zC + (long long)(gmb + r) * ldc + gn] = f2bf(e);
          rs[r] += e;
        }
      }
#pragma unroll
      for (int r = 0; r < 4; ++r) {
        float s = rs[r];
        s += __shfl_xor(s, 1); s += __shfl_xor(s, 2);
        s += __shfl_xor(s, 4); s += __shfl_xor(s, 8);
        if (col == 0)
          atomicAdd(&lsum[(long long)blockIdx.z * 2048 + gmb + r], s);
      }
    }
  } else if constexpr (MODE == 4) {
#pragma unroll
    for (int i = 0; i < MF; ++i) {
      const int gmb = m0 + (i / MFH) * 128 + wmi * (WTM / 2) + (i % MFH) * 16 + rq;
      float inv[4];
#pragma unroll
      for (int r = 0; r < 4; ++r)
        inv[r] = 1.0f / lsum[(long long)blockIdx.z * 2048 + gmb + r];
#pragma unroll
      for (int j = 0; j < 4; ++j) {
        const int gn = n0 + (j >> 1) * (BN / 2) + wni * 32 + (j & 1) * 16 + col;
#pragma unroll
        for (int r = 0; r < 4; ++r)
          ((u16*)C)[zC + (long long)(gmb + r) * ldc + gn] = f2bf(acc[i][j][r] * inv[r]);
      }
    }
  } else if constexpr (MODE == 3) {
    const int sect = n0 >> 10;  // 0=Q 1=K 2=V (n0 256-aligned, uniform)
#pragma unroll
    for (int i = 0; i < MF; ++i) {
      const int gmb = m0 + (i / MFH) * 128 + wmi * (WTM / 2) + (i % MFH) * 16 + rq;
#pragma unroll
      for (int j = 0; j < 4; ++j) {
        const int gn = n0 + (j >> 1) * (BN / 2) + wni * 32 + (j & 1) * 16 + col;
        const int nb = gn & 1023;
        const float bvv = (sect == 0) ? bias[nb] : (sect == 1) ? bias2[nb] : bias3[nb];
#pragma unroll
        for (int r = 0; r < 4; ++r) {
          const int gm = gmb + r;
          const float v = acc[i][j][r] + bvv;
          if (sect == 0) {
            ((u16*)C)[(long long)gm * 1024 + nb] = f2bf(v);
          } else if (sect == 1) {
            ((u16*)C2)[(long long)gm * 1024 + nb] = f2bf(v);
          } else {
            const int bb = gm >> 11, tt = gm & 2047;
            ((u16*)C3)[((long long)bb << 21) + (long long)nb * 2048 + tt] = f2bf(v);
          }
        }
      }
    }
  } else {  // MODE == 2: fp32 row-major + bias
#pragma unroll
    for (int i = 0; i < MF; ++i) {
      const int gmb = m0 + (i / MFH) * 128 + wmi * (WTM / 2) + (i % MFH) * 16 + rq;
#pragma unroll
      for (int j = 0; j < 4; ++j) {
        const int gn = n0 + (j >> 1) * (BN / 2) + wni * 32 + (j & 1) * 16 + col;
        const float bvv = bias[gn];
#pragma unroll
        for (int r = 0; r < 4; ++r)
          ((float*)C)[zC + (long long)(gmb + r) * ldc + gn] = acc[i][j][r] + bvv;
      }
    }
  }
}

extern "C" void kernel_launch(void* const* d_in, const int* in_sizes, int n_in,
                              void* d_out, int out_size, void* d_ws, size_t ws_size,
                              hipStream_t stream) {
  (void)in_sizes; (void)n_in; (void)out_size; (void)ws_size;
  const float* feat = (const float*)d_in[0];
  const float* Wq = (const float*)d_in[1];
  const float* bq = (const float*)d_in[2];
  const float* Wk = (const float*)d_in[3];
  const float* bk = (const float*)d_in[4];
  const float* Wv = (const float*)d_in[5];
  const float* bv = (const float*)d_in[6];
  const float* Wo = (const float*)d_in[7];
  const float* bo = (const float*)d_in[8];
  float* out = (float*)d_out;

  char* ws = (char*)d_ws;
  const unsigned long long MB = 1024ull * 1024ull;
  u16* Xbf  = (u16*)(ws);
  u16* Wcat = (u16*)(ws + 16 * MB);           // Wq|Wk|Wv|Wo bf16
  u16* Wob  = Wcat + 3ll * 1024 * 1024;
  u16* Q    = (u16*)(ws + 24 * MB);           // reused as attn later
  u16* Kbuf = (u16*)(ws + 40 * MB);
  u16* Vt   = (u16*)(ws + 56 * MB);
  u16* P    = (u16*)(ws + 72 * MB);           // dense bf16 [4][2048,2048]
  float* lsum = (float*)(ws + 104 * MB);      // [8192]
  u16* attn = Q;

  // casts (features + 4 weights) + lsum zeroing in one launch
  cast_all<<<12320, 256, 0, stream>>>((const float4*)feat, (const float4*)Wq,
                                      (const float4*)Wk, (const float4*)Wv,
                                      (const float4*)Wo, (ushort4*)Xbf,
                                      (ushort4*)Wcat, lsum);

  // fused QKV projection: N=3072 over Wq|Wk|Wv; V written transposed
  gemm8p<3, 256><<<dim3(12, 32, 1), 512, 0, stream>>>(
      Xbf, Wcat, Q, Kbuf, Vt, bq, bk, bv, nullptr,
      8192, 3072, 1024, 1024, 0, 1.f, 0, 0, 0);

  // P~ = exp(Q K^T * 0.125) bf16 + row sums -> lsum (all 4 batches)
  gemm8p<5, 256><<<dim3(8, 8, 4), 512, 0, stream>>>(
      Q, Kbuf, P, nullptr, nullptr, nullptr, nullptr, nullptr, lsum,
      2048, 2048, 1024, 1024, 2048, 0.125f,
      2048ll * 1024, 2048ll * 1024, 2048ll * 2048);

  // attn = (P~ @ V) / lsum  (batched; B operand is Vt)
  gemm8p<4, 128><<<dim3(8, 8, 4), 512, 0, stream>>>(
      P, Vt, attn, nullptr, nullptr, nullptr, nullptr, nullptr, lsum,
      2048, 1024, 2048, 2048, 1024, 1.f,
      2048ll * 2048, 1024ll * 2048, 2048ll * 1024);

  // out = attn @ Wo^T + bo  (fp32 output)
  gemm8p<2, 128><<<dim3(8, 32, 1), 512, 0, stream>>>(
      attn, Wob, out, nullptr, nullptr, bo, nullptr, nullptr, nullptr,
      8192, 1024, 1024, 1024, 1024, 1.f, 0, 0, 0);
}

// Round 3
// 310.186 us; speedup vs baseline: 1.1156x; 1.0765x over previous
//
#include <hip/hip_runtime.h>

// B=4, S=2048, D=1024, scale = 1/sqrt(64) = 0.125
// Workspace layout (105 MB):
//   [0,16M)    Xbf  : features bf16              [8192,1024]
//   [16M,24M)  Wcat bf16: Wq|Wk|Wv|Wo            4 x [1024,1024]
//   [24M,40M)  Q bf16 [8192,1024]  -> reused as attn
//   [40M,56M)  K bf16
//   [56M,72M)  Vt bf16 (V transposed)            [4][1024,2048]
//   [72M,104M) P~ bf16 dense [4][2048,2048]
//   [104M,+32K) lsum fp32 [8192]
//
// R9: R6 128^2 base (measured 308us total / 570 TF QKV) + explicit LDS
// double-buffer with counted waits (catalog T3-minimum 2-phase recipe):
//   iter t: STAGE(buf^1, t+1) -> ds_reads+MFMA on buf (compiler-scheduled
//           lgkm waits) -> s_waitcnt vmcnt(0) -> s_barrier -> buf ^= 1
// vs R6's stage -> syncthreads (vmcnt(0) drain BEFORE compute, full memory
// latency exposed every K-step) -> compute -> syncthreads. One barrier per
// K-step instead of two; staging latency hidden under the current tile's
// ~2500 cyc of reads+MFMA. WAR-safe: every wave executes vmcnt(0) before
// its barrier arrival, so at release all staging writes have landed; buf is
// only overwritten one iteration after its last read, behind the barrier.
// LDS 64KB -> 2 blocks/CU (vs R6's 5): dbuf replaces the lost TLP.
// Rotation swizzle kept (measured 0 bank conflicts). R1/R2's 8-phase 256^2
// port abandoned: 18.5% MfmaUtil vs model's 45%, mechanism unexplained.
//
// MODE 2: fp32 row-major + bias (out-proj)
// MODE 3: fused QKV epilogue (Q->C, K->C2, Vt->C3 transposed-batched)
// MODE 4: bf16 row-major, acc * 1/lsum[row] (PV normalize)
// MODE 5: exp(scale*acc) bf16 + atomic row sums (scores)

using u16 = unsigned short;
typedef __bf16 bf16x8 __attribute__((ext_vector_type(8)));
typedef float f32x4 __attribute__((ext_vector_type(4)));

#define AS1 __attribute__((address_space(1)))
#define AS3 __attribute__((address_space(3)))

__device__ inline u16 f2bf(float f) {
  union { float f; unsigned int u; } c; c.f = f;
  unsigned int u = c.u;
  u += 0x7fffu + ((u >> 16) & 1u);   // round-to-nearest-even
  return (u16)(u >> 16);
}

// one launch: casts features + all 4 weight matrices, and zeroes lsum
__global__ __launch_bounds__(256) void cast_all(
    const float4* __restrict__ feat, const float4* __restrict__ wq,
    const float4* __restrict__ wk, const float4* __restrict__ wv,
    const float4* __restrict__ wo, ushort4* __restrict__ xbf,
    ushort4* __restrict__ wcat, float* __restrict__ lsum) {
  const int b = blockIdx.x, tx = threadIdx.x;
  if (b >= 12288) {                      // 32 trailing blocks zero lsum[8192]
    lsum[(b - 12288) * 256 + tx] = 0.f;
    return;
  }
  const float4* src; ushort4* dst; int idx;
  if (b < 8192) { src = feat; dst = xbf; idx = b * 256 + tx; }
  else {
    const int w = (b - 8192) >> 10, loc = ((b - 8192) & 1023) * 256 + tx;
    src = (w == 0) ? wq : (w == 1) ? wk : (w == 2) ? wv : wo;
    dst = wcat + w * 262144; idx = loc;
  }
  float4 v = src[idx];
  ushort4 o;
  o.x = f2bf(v.x); o.y = f2bf(v.y); o.z = f2bf(v.z); o.w = f2bf(v.w);
  dst[idx] = o;
}

template <int MODE>
__global__ __launch_bounds__(256) void gemm_bt(
    const u16* __restrict__ A, const u16* __restrict__ Bm, void* __restrict__ C,
    void* __restrict__ C2, void* __restrict__ C3,
    const float* __restrict__ bias, const float* __restrict__ bias2,
    const float* __restrict__ bias3, float* __restrict__ lsum,
    int M, int N, int K, int lda, int ldc,
    float scale,
    long long sA, long long sB, long long sC)
{
  __shared__ u16 As[2 * 128 * 64];
  __shared__ u16 Bs[2 * 128 * 64];
  const int tx = threadIdx.x;
  const int wave = tx >> 6, lane = tx & 63;
  const int wm = (wave >> 1) * 64, wn = (wave & 1) * 64;
  const int m0 = blockIdx.y * 128, n0 = blockIdx.x * 128;
  const u16* Ab = A + blockIdx.z * sA + (long long)m0 * lda;
  const u16* Bb = Bm + blockIdx.z * sB + (long long)n0 * K;

  f32x4 acc[4][4] = {};

  // staging: issue t in 0..3, physical chunk c = t*256 + wave*64 + lane
  // r = c>>3 = t*32 + wave*8 + (lane>>3); slot p = lane&7; quad q=(p-r)&7
  int rT[4], qT[4];
#pragma unroll
  for (int t = 0; t < 4; ++t) {
    rT[t] = t * 32 + wave * 8 + (lane >> 3);
    qT[t] = (((lane & 7) - rT[t]) & 7) << 3;   // element offset of 8-elem quad
  }
  // wave-uniform LDS dest base for issue t (HW adds lane*16B)
  const int ldsT[4] = {wave * 512, 2048 + wave * 512, 4096 + wave * 512,
                       6144 + wave * 512};

  const int fr = lane & 15, fq = lane >> 4;

  auto stage = [&](int k0, int buf) {
#pragma unroll
    for (int t = 0; t < 4; ++t) {
      __builtin_amdgcn_global_load_lds(
          (const AS1 void*)(Ab + (long long)rT[t] * lda + k0 + qT[t]),
          (AS3 void*)(As + buf * 8192 + ldsT[t]), 16, 0, 0);
      __builtin_amdgcn_global_load_lds(
          (const AS1 void*)(Bb + (long long)rT[t] * K + k0 + qT[t]),
          (AS3 void*)(Bs + buf * 8192 + ldsT[t]), 16, 0, 0);
    }
  };

  // prologue: tile 0 into buf 0, drain, fence
  stage(0, 0);
  asm volatile("s_waitcnt vmcnt(0)" ::: "memory");
  __builtin_amdgcn_s_barrier();

  int cur = 0;
  for (int k0 = 0; k0 < K; k0 += 64) {
    if (k0 + 64 < K) stage(k0 + 64, cur ^ 1);   // issue next-tile loads first

    const u16* Ac = As + cur * 8192;
    const u16* Bc = Bs + cur * 8192;
    __builtin_amdgcn_s_setprio(1);
#pragma unroll
    for (int s = 0; s < 2; ++s) {
      bf16x8 af[4], bfv[4];
#pragma unroll
      for (int i = 0; i < 4; ++i) {
        const int Ra = wm + i * 16 + fr;
        const int Rb = wn + i * 16 + fr;
        af[i]  = *(const bf16x8*)(Ac + Ra * 64 + (((s * 4 + fq + Ra) & 7) << 3));
        bfv[i] = *(const bf16x8*)(Bc + Rb * 64 + (((s * 4 + fq + Rb) & 7) << 3));
      }
#pragma unroll
      for (int i = 0; i < 4; ++i)
#pragma unroll
        for (int j = 0; j < 4; ++j)
          acc[i][j] = __builtin_amdgcn_mfma_f32_16x16x32_bf16(af[i], bfv[j], acc[i][j], 0, 0, 0);
    }
    __builtin_amdgcn_s_setprio(0);

    // next tile's staging loads have landed (each wave waits its own; the
    // barrier joins all waves, so buf^1 is fully populated after release).
    asm volatile("s_waitcnt vmcnt(0)" ::: "memory");
    __builtin_amdgcn_s_barrier();
    cur ^= 1;
  }

  // epilogue: C/D layout col=lane&15, row=(lane>>4)*4+reg
  const int col = lane & 15, rq = (lane >> 4) << 2;
  const long long zC = (long long)blockIdx.z * sC;

  if constexpr (MODE == 5) {
    // exp + bf16 store + per-row sum (reduce over 16 col-lanes, atomicAdd)
    float rsum[4][4] = {};   // [i][r]
#pragma unroll
    for (int i = 0; i < 4; ++i) {
#pragma unroll
      for (int j = 0; j < 4; ++j) {
        const int gn = n0 + wn + j * 16 + col;
#pragma unroll
        for (int r = 0; r < 4; ++r) {
          const int gm = m0 + wm + i * 16 + rq + r;
          const float e = __expf(acc[i][j][r] * scale);
          ((u16*)C)[zC + (long long)gm * ldc + gn] = f2bf(e);
          rsum[i][r] += e;
        }
      }
    }
#pragma unroll
    for (int i = 0; i < 4; ++i) {
#pragma unroll
      for (int r = 0; r < 4; ++r) {
        float s = rsum[i][r];
        s += __shfl_xor(s, 1); s += __shfl_xor(s, 2);
        s += __shfl_xor(s, 4); s += __shfl_xor(s, 8);
        if (col == 0)
          atomicAdd(&lsum[(long long)blockIdx.z * 2048 + m0 + wm + i * 16 + rq + r], s);
      }
    }
  } else if constexpr (MODE == 4) {
    float inv[4][4];
#pragma unroll
    for (int i = 0; i < 4; ++i)
#pragma unroll
      for (int r = 0; r < 4; ++r)
        inv[i][r] = 1.0f / lsum[(long long)blockIdx.z * 2048 + m0 + wm + i * 16 + rq + r];
#pragma unroll
    for (int i = 0; i < 4; ++i)
#pragma unroll
      for (int j = 0; j < 4; ++j) {
        const int gn = n0 + wn + j * 16 + col;
#pragma unroll
        for (int r = 0; r < 4; ++r) {
          const int gm = m0 + wm + i * 16 + rq + r;
          ((u16*)C)[zC + (long long)gm * ldc + gn] = f2bf(acc[i][j][r] * inv[i][r]);
        }
      }
  } else if constexpr (MODE == 3) {
    const int sect = n0 >> 10;  // 0=Q 1=K 2=V (n0 128-aligned, uniform)
#pragma unroll
    for (int i = 0; i < 4; ++i) {
#pragma unroll
      for (int j = 0; j < 4; ++j) {
        const int gn = n0 + wn + j * 16 + col;
        const int nb = gn & 1023;
        const float bv = (sect == 0) ? bias[nb] : (sect == 1) ? bias2[nb] : bias3[nb];
#pragma unroll
        for (int r = 0; r < 4; ++r) {
          const int gm = m0 + wm + i * 16 + rq + r;
          const float v = acc[i][j][r] + bv;
          if (sect == 0) {
            ((u16*)C)[(long long)gm * 1024 + nb] = f2bf(v);
          } else if (sect == 1) {
            ((u16*)C2)[(long long)gm * 1024 + nb] = f2bf(v);
          } else {
            const int bb = gm >> 11, t = gm & 2047;
            ((u16*)C3)[((long long)bb << 21) + (long long)nb * 2048 + t] = f2bf(v);
          }
        }
      }
    }
  } else {  // MODE == 2: fp32 row-major + bias
#pragma unroll
    for (int i = 0; i < 4; ++i) {
#pragma unroll
      for (int j = 0; j < 4; ++j) {
        const int gn = n0 + wn + j * 16 + col;
        const float bv = bias[gn];
#pragma unroll
        for (int r = 0; r < 4; ++r) {
          const int gm = m0 + wm + i * 16 + rq + r;
          ((float*)C)[zC + (long long)gm * ldc + gn] = acc[i][j][r] + bv;
        }
      }
    }
  }
}

extern "C" void kernel_launch(void* const* d_in, const int* in_sizes, int n_in,
                              void* d_out, int out_size, void* d_ws, size_t ws_size,
                              hipStream_t stream) {
  (void)in_sizes; (void)n_in; (void)out_size; (void)ws_size;
  const float* feat = (const float*)d_in[0];
  const float* Wq = (const float*)d_in[1];
  const float* bq = (const float*)d_in[2];
  const float* Wk = (const float*)d_in[3];
  const float* bk = (const float*)d_in[4];
  const float* Wv = (const float*)d_in[5];
  const float* bv = (const float*)d_in[6];
  const float* Wo = (const float*)d_in[7];
  const float* bo = (const float*)d_in[8];
  float* out = (float*)d_out;

  char* ws = (char*)d_ws;
  const unsigned long long MB = 1024ull * 1024ull;
  u16* Xbf  = (u16*)(ws);
  u16* Wcat = (u16*)(ws + 16 * MB);           // Wq|Wk|Wv|Wo bf16
  u16* Wob  = Wcat + 3ll * 1024 * 1024;
  u16* Q    = (u16*)(ws + 24 * MB);           // reused as attn later
  u16* Kbuf = (u16*)(ws + 40 * MB);
  u16* Vt   = (u16*)(ws + 56 * MB);
  u16* P    = (u16*)(ws + 72 * MB);           // dense bf16 [4][2048,2048]
  float* lsum = (float*)(ws + 104 * MB);      // [8192]
  u16* attn = Q;

  dim3 blk(256);

  // casts (features + 4 weights) + lsum zeroing in one launch
  cast_all<<<12320, blk, 0, stream>>>((const float4*)feat, (const float4*)Wq,
                                      (const float4*)Wk, (const float4*)Wv,
                                      (const float4*)Wo, (ushort4*)Xbf,
                                      (ushort4*)Wcat, lsum);

  // fused QKV projection: N=3072 over Wq|Wk|Wv; V written transposed per batch
  gemm_bt<3><<<dim3(24, 64, 1), blk, 0, stream>>>(
      Xbf, Wcat, Q, Kbuf, Vt, bq, bk, bv, nullptr,
      8192, 3072, 1024, 1024, 0, 1.f, 0, 0, 0);

  // P~ = exp(Q K^T * 0.125) bf16 + row sums -> lsum (all 4 batches)
  gemm_bt<5><<<dim3(16, 16, 4), blk, 0, stream>>>(
      Q, Kbuf, P, nullptr, nullptr, nullptr, nullptr, nullptr, lsum,
      2048, 2048, 1024, 1024, 2048, 0.125f,
      2048ll * 1024, 2048ll * 1024, 2048ll * 2048);

  // attn = (P~ @ V) / lsum  (batched; B operand is Vt)
  gemm_bt<4><<<dim3(8, 16, 4), blk, 0, stream>>>(
      P, Vt, attn, nullptr, nullptr, nullptr, nullptr, nullptr, lsum,
      2048, 1024, 2048, 2048, 1024, 1.f,
      2048ll * 2048, 1024ll * 2048, 2048ll * 1024);

  // out = attn @ Wo^T + bo  (fp32 output)
  gemm_bt<2><<<dim3(8, 64, 1), blk, 0, stream>>>(
      attn, Wob, out, nullptr, nullptr, bo, nullptr, nullptr, nullptr,
      8192, 1024, 1024, 1024, 1024, 1.f, 0, 0, 0);
}